// Round 1
// baseline (1040.998 us; speedup 1.0000x reference)
//
#include <hip/hip_runtime.h>

// Graph: N=100000 nodes, E=1280000 edges; dims 128 -> 64 -> 64 -> 40.
constexpr int NN = 100000;
constexpr int NE = 1280000;
constexpr int NP = 100352;   // padded N for workspace layout (multiple of 256)

// ---------------------------------------------------------------------------
// Degree accumulation (float atomics; avg degree 12.8 so contention is low)
// ---------------------------------------------------------------------------
__global__ __launch_bounds__(256) void deg_kernel(
    const int* __restrict__ src, const int* __restrict__ dst,
    float* __restrict__ deg_out, float* __restrict__ deg_in) {
  int i = blockIdx.x * 256 + threadIdx.x;
  if (i < NE) {
    atomicAdd(&deg_out[src[i]], 1.0f);
    atomicAdd(&deg_in[dst[i]], 1.0f);
  }
}

// In-place deg -> clip(deg,1)^-0.5
__global__ __launch_bounds__(256) void norm_kernel(
    float* __restrict__ norm_out, float* __restrict__ norm_in) {
  int i = blockIdx.x * 256 + threadIdx.x;
  if (i < NN) {
    norm_out[i] = rsqrtf(fmaxf(norm_out[i], 1.0f));
    norm_in[i]  = rsqrtf(fmaxf(norm_in[i], 1.0f));
  }
}

// ---------------------------------------------------------------------------
// Fused GEMM:  out[row, :] = ( PRE(in[row, :]) @ W ) * norm_out[row]
//   PRE (layers 1,2): v = relu(in * norm_in[row] + bias_prev[k])  (prev epilogue)
// Tile: 64 rows x 64 cols (COLS<=64, padded with zero W cols), K-chunks of 32.
// x staged TRANSPOSED in LDS (stride 68 -> 16B-aligned float4 reads, banks
// spread 4k+4tr -> conflict-free); W rows are 64 floats -> float4 reads with
// 4-way broadcast. Inner loop: 2x ds_read_b128 per 16 FMAs -> FMA-issue bound.
// ---------------------------------------------------------------------------
template <int K, int COLS, bool PRE>
__global__ __launch_bounds__(256) void gemm_kernel(
    const float* __restrict__ in, const float* __restrict__ W,
    const float* __restrict__ bias_prev, const float* __restrict__ norm_in,
    const float* __restrict__ norm_out, float* __restrict__ out) {
  constexpr int KC = 32;
  constexpr int XS = 68;  // 64 rows + pad; 68*4B = 272B, 16B-aligned rows
  __shared__ float Wl[K][64];
  __shared__ float xt[KC][XS];

  const int tid = threadIdx.x;
  // Load W into LDS, zero-padding cols >= COLS (layer 2: COLS=40)
  for (int i = tid; i < K * 64; i += 256) {
    int k = i >> 6, c = i & 63;
    Wl[k][c] = (c < COLS) ? W[k * COLS + c] : 0.0f;
  }

  const int tc = tid & 15;   // col group: cols 4*tc .. 4*tc+3
  const int tr = tid >> 4;   // row group: rows 4*tr .. 4*tr+3
  const int row0 = blockIdx.x * 64;

  float acc[4][4] = {};

  for (int kc = 0; kc < K; kc += KC) {
    // Stage 64 rows x 32 ks, transposed: xt[k][row]
    // elem = i*256+tid -> row = elem>>5, kk = elem&31 (coalesced global reads)
#pragma unroll
    for (int i = 0; i < 8; ++i) {
      int elem = i * 256 + tid;
      int r = elem >> 5;
      int kk = elem & 31;
      int grow = row0 + r;
      float v = 0.0f;
      if (grow < NN) {
        v = in[grow * K + kc + kk];
        if constexpr (PRE)
          v = fmaxf(fmaf(v, norm_in[grow], bias_prev[kc + kk]), 0.0f);
      }
      xt[kk][r] = v;
    }
    __syncthreads();
#pragma unroll
    for (int kk = 0; kk < KC; ++kk) {
      float4 xv = *(const float4*)&xt[kk][4 * tr];
      float4 wv = *(const float4*)&Wl[kc + kk][4 * tc];
      float xa[4] = {xv.x, xv.y, xv.z, xv.w};
      float wa[4] = {wv.x, wv.y, wv.z, wv.w};
#pragma unroll
      for (int r = 0; r < 4; ++r)
#pragma unroll
        for (int c = 0; c < 4; ++c)
          acc[r][c] = fmaf(xa[r], wa[c], acc[r][c]);
    }
    __syncthreads();
  }

  // Epilogue: scale by norm_out (commutes with the linear GEMM)
#pragma unroll
  for (int r = 0; r < 4; ++r) {
    int grow = row0 + 4 * tr + r;
    if (grow < NN) {
      float no = norm_out[grow];
#pragma unroll
      for (int c = 0; c < 4; ++c) {
        int col = 4 * tc + c;
        if (col < COLS) out[grow * COLS + col] = acc[r][c] * no;
      }
    }
  }
}

// ---------------------------------------------------------------------------
// SpMM scatter: agg[dst] += m[src], one thread per (edge, feature).
// Wave-uniform edge index for C=64 -> broadcast src/dst loads; 256B coalesced
// gather per edge; device-scope float atomics into agg.
// ---------------------------------------------------------------------------
template <int C>
__global__ __launch_bounds__(256) void scatter_kernel(
    const float* __restrict__ m, const int* __restrict__ src,
    const int* __restrict__ dst, float* __restrict__ agg) {
  int idx = blockIdx.x * 256 + threadIdx.x;
  if (idx >= NE * C) return;
  int e = idx / C;          // constant divisor -> magic-mul
  int f = idx - e * C;
  int s = src[e];
  int d = dst[e];
  atomicAdd(&agg[d * C + f], m[s * C + f]);
}

// Final epilogue: out = agg * norm_in + b2  (no activation on output layer)
__global__ __launch_bounds__(256) void final_kernel(
    const float* __restrict__ agg, const float* __restrict__ norm_in,
    const float* __restrict__ b2, float* __restrict__ out) {
  int i = blockIdx.x * 256 + threadIdx.x;
  if (i < NN * 40) {
    int row = i / 40;
    int col = i - row * 40;
    out[i] = fmaf(agg[i], norm_in[row], b2[col]);
  }
}

// ---------------------------------------------------------------------------
extern "C" void kernel_launch(void* const* d_in, const int* in_sizes, int n_in,
                              void* d_out, int out_size, void* d_ws, size_t ws_size,
                              hipStream_t stream) {
  const float* x    = (const float*)d_in[0];
  const float* W0   = (const float*)d_in[1];
  const float* b0   = (const float*)d_in[2];
  const float* W1   = (const float*)d_in[3];
  const float* b1   = (const float*)d_in[4];
  const float* W2   = (const float*)d_in[5];
  const float* b2   = (const float*)d_in[6];
  const int*   esrc = (const int*)d_in[7];
  const int*   edst = (const int*)d_in[8];
  float* out = (float*)d_out;

  // Workspace layout (floats): norms (2*NP) + m (N*64) + agg (N*64) = 52.0 MB
  float* f        = (float*)d_ws;
  float* norm_out = f;
  float* norm_in  = f + NP;
  float* m        = f + 2 * NP;
  float* agg      = m + NN * 64;

  // Degrees + norms (deg accumulated in-place into the norm buffers)
  hipMemsetAsync(norm_out, 0, 2 * NP * sizeof(float), stream);
  deg_kernel<<<(NE + 255) / 256, 256, 0, stream>>>(esrc, edst, norm_out, norm_in);
  norm_kernel<<<(NN + 255) / 256, 256, 0, stream>>>(norm_out, norm_in);

  const int gb = (NN + 63) / 64;

  // Layer 0: m = (x * norm_out) @ W0
  gemm_kernel<128, 64, false><<<gb, 256, 0, stream>>>(x, W0, nullptr, nullptr, norm_out, m);
  hipMemsetAsync(agg, 0, (size_t)NN * 64 * sizeof(float), stream);
  scatter_kernel<64><<<(NE * 64 + 255) / 256, 256, 0, stream>>>(m, esrc, edst, agg);

  // Layer 1: h0 = relu(agg*norm_in + b0) fused into GEMM load; m = (h0*norm_out) @ W1
  gemm_kernel<64, 64, true><<<gb, 256, 0, stream>>>(agg, W1, b0, norm_in, norm_out, m);
  hipMemsetAsync(agg, 0, (size_t)NN * 64 * sizeof(float), stream);
  scatter_kernel<64><<<(NE * 64 + 255) / 256, 256, 0, stream>>>(m, esrc, edst, agg);

  // Layer 2: h1 = relu(agg*norm_in + b1) fused; m = (h1*norm_out) @ W2  (40 cols)
  gemm_kernel<64, 40, true><<<gb, 256, 0, stream>>>(agg, W2, b1, norm_in, norm_out, m);
  hipMemsetAsync(agg, 0, (size_t)NN * 40 * sizeof(float), stream);
  scatter_kernel<40><<<(NE * 40 + 255) / 256, 256, 0, stream>>>(m, esrc, edst, agg);

  // Output epilogue: out = agg * norm_in + b2
  final_kernel<<<(NN * 40 + 255) / 256, 256, 0, stream>>>(agg, norm_in, b2, out);
}

// Round 2
// 492.446 us; speedup vs baseline: 2.1139x; 2.1139x over previous
//
#include <hip/hip_runtime.h>

// GraphConv 3-layer GCN: N=100000 nodes, E=1280000 edges; dims 128->64->64->40.
constexpr int NN = 100000;
constexpr int NE = 1280000;
constexpr int NP = 100352;       // padded N (= 98 * 1024)
constexpr int NBLK = NP / 1024;  // 98 scan chunks

// ---------------------------------------------------------------------------
// Degree histograms (int atomics, L2-friendly, low contention)
// ---------------------------------------------------------------------------
__global__ __launch_bounds__(256) void hist_kernel(
    const int* __restrict__ src, const int* __restrict__ dst,
    int* __restrict__ cnt_out, int* __restrict__ cnt_in) {
  int e = blockIdx.x * 256 + threadIdx.x;
  if (e < NE) {
    atomicAdd(&cnt_out[src[e]], 1);
    atomicAdd(&cnt_in[dst[e]], 1);
  }
}

// norms = clip(deg,1)^-0.5
__global__ __launch_bounds__(256) void norm_kernel(
    const int* __restrict__ cnt_out, const int* __restrict__ cnt_in,
    float* __restrict__ norm_out, float* __restrict__ norm_in) {
  int i = blockIdx.x * 256 + threadIdx.x;
  if (i < NN) {
    norm_out[i] = rsqrtf(fmaxf((float)cnt_out[i], 1.0f));
    norm_in[i]  = rsqrtf(fmaxf((float)cnt_in[i], 1.0f));
  }
}

// ---------------------------------------------------------------------------
// Two-level exclusive scan of cnt_in -> row_ptr (and cursor copy)
// ---------------------------------------------------------------------------
__global__ __launch_bounds__(256) void chunk_sum_kernel(
    const int* __restrict__ cnt, int* __restrict__ partial) {
  int t = threadIdx.x;
  int base = blockIdx.x * 1024 + t * 4;
  int s = 0;
#pragma unroll
  for (int j = 0; j < 4; ++j) {
    int gi = base + j;
    s += (gi < NN) ? cnt[gi] : 0;
  }
  __shared__ int r[256];
  r[t] = s;
  __syncthreads();
  for (int off = 128; off > 0; off >>= 1) {
    if (t < off) r[t] += r[t + off];
    __syncthreads();
  }
  if (t == 0) partial[blockIdx.x] = r[0];
}

__global__ __launch_bounds__(128) void partial_scan_kernel(int* __restrict__ partial) {
  int t = threadIdx.x;
  int v = (t < NBLK) ? partial[t] : 0;
  __shared__ int s[128];
  s[t] = v;
  __syncthreads();
  for (int off = 1; off < 128; off <<= 1) {
    int add = (t >= off) ? s[t - off] : 0;
    __syncthreads();
    s[t] += add;
    __syncthreads();
  }
  if (t < NBLK) partial[t] = s[t] - v;  // exclusive
}

__global__ __launch_bounds__(256) void chunk_scan_kernel(
    const int* __restrict__ cnt, const int* __restrict__ partial,
    int* __restrict__ row_ptr, int* __restrict__ cursor) {
  int t = threadIdx.x;
  int base = blockIdx.x * 1024 + t * 4;
  int c[4];
#pragma unroll
  for (int j = 0; j < 4; ++j) {
    int gi = base + j;
    c[j] = (gi < NN) ? cnt[gi] : 0;
  }
  int tsum = c[0] + c[1] + c[2] + c[3];
  __shared__ int s[256];
  s[t] = tsum;
  __syncthreads();
  for (int off = 1; off < 256; off <<= 1) {
    int add = (t >= off) ? s[t - off] : 0;
    __syncthreads();
    s[t] += add;
    __syncthreads();
  }
  int run = s[t] - tsum + partial[blockIdx.x];
#pragma unroll
  for (int j = 0; j < 4; ++j) {
    int gi = base + j;
    if (gi <= NN) {
      row_ptr[gi] = run;
      cursor[gi] = run;
    }
    run += c[j];
  }
}

// Scatter edge srcs into dst-sorted CSR slots
__global__ __launch_bounds__(256) void fill_kernel(
    const int* __restrict__ src, const int* __restrict__ dst,
    int* __restrict__ cursor, int* __restrict__ csr_src) {
  int e = blockIdx.x * 256 + threadIdx.x;
  if (e < NE) {
    int pos = atomicAdd(&cursor[dst[e]], 1);
    csr_src[pos] = src[e];
  }
}

// ---------------------------------------------------------------------------
// GEMM:  out[row, :] = PRE(in[row, :]) @ W     (PRE = *norm_out for layer 0)
// 64x64 tile, K-chunks of 32, x staged transposed in LDS (stride 68).
// ---------------------------------------------------------------------------
template <int K, int COLS, bool SCALE>
__global__ __launch_bounds__(256) void gemm_kernel(
    const float* __restrict__ in, const float* __restrict__ W,
    const float* __restrict__ norm_out, float* __restrict__ out) {
  constexpr int KC = 32;
  constexpr int XS = 68;
  __shared__ float Wl[K][64];
  __shared__ float xt[KC][XS];

  const int tid = threadIdx.x;
  for (int i = tid; i < K * 64; i += 256) {
    int k = i >> 6, c = i & 63;
    Wl[k][c] = (c < COLS) ? W[k * COLS + c] : 0.0f;
  }

  const int tc = tid & 15;
  const int tr = tid >> 4;
  const int row0 = blockIdx.x * 64;

  float acc[4][4] = {};

  for (int kc = 0; kc < K; kc += KC) {
#pragma unroll
    for (int i = 0; i < 8; ++i) {
      int elem = i * 256 + tid;
      int r = elem >> 5;
      int kk = elem & 31;
      int grow = row0 + r;
      float v = 0.0f;
      if (grow < NN) {
        v = in[grow * K + kc + kk];
        if constexpr (SCALE) v *= norm_out[grow];
      }
      xt[kk][r] = v;
    }
    __syncthreads();
#pragma unroll
    for (int kk = 0; kk < KC; ++kk) {
      float4 xv = *(const float4*)&xt[kk][4 * tr];
      float4 wv = *(const float4*)&Wl[kc + kk][4 * tc];
      float xa[4] = {xv.x, xv.y, xv.z, xv.w};
      float wa[4] = {wv.x, wv.y, wv.z, wv.w};
#pragma unroll
      for (int r = 0; r < 4; ++r)
#pragma unroll
        for (int c = 0; c < 4; ++c)
          acc[r][c] = fmaf(xa[r], wa[c], acc[r][c]);
    }
    __syncthreads();
  }

#pragma unroll
  for (int r = 0; r < 4; ++r) {
    int grow = row0 + 4 * tr + r;
    if (grow < NN) {
#pragma unroll
      for (int c = 0; c < 4; ++c) {
        int col = 4 * tc + c;
        if (col < COLS) out[grow * COLS + col] = acc[r][c];
      }
    }
  }
}

// ---------------------------------------------------------------------------
// CSR gather aggregation, one wave per node, lane = feature.
// RELU mode:  out = relu(acc*norm_in + bias) * norm_out   (feeds next GEMM)
// !RELU:      out = acc*norm_in + bias                    (final output)
// Coalesced 256B row gathers from m (L2/L3-resident); no atomics; one write.
// ---------------------------------------------------------------------------
template <int C, bool RELU>
__global__ __launch_bounds__(256) void gather_kernel(
    const float* __restrict__ m, const int* __restrict__ row_ptr,
    const int* __restrict__ csr_src, const float* __restrict__ norm_in,
    const float* __restrict__ norm_out, const float* __restrict__ bias,
    float* __restrict__ outp) {
  int node = blockIdx.x * 4 + (threadIdx.x >> 6);
  int lane = threadIdx.x & 63;
  if (node >= NN) return;
  int beg = row_ptr[node];
  int end = row_ptr[node + 1];

  float a0 = 0.f, a1 = 0.f, a2 = 0.f, a3 = 0.f;
  int i = beg;
  for (; i + 4 <= end; i += 4) {
    int s0 = csr_src[i], s1 = csr_src[i + 1], s2 = csr_src[i + 2], s3 = csr_src[i + 3];
    if (lane < C) {
      a0 += m[s0 * C + lane];
      a1 += m[s1 * C + lane];
      a2 += m[s2 * C + lane];
      a3 += m[s3 * C + lane];
    }
  }
  for (; i < end; ++i) {
    int s = csr_src[i];
    if (lane < C) a0 += m[s * C + lane];
  }
  float acc = (a0 + a1) + (a2 + a3);

  if (lane < C) {
    float v = fmaf(acc, norm_in[node], bias[lane]);
    if constexpr (RELU) v = fmaxf(v, 0.f) * norm_out[node];
    outp[node * C + lane] = v;
  }
}

// ---------------------------------------------------------------------------
extern "C" void kernel_launch(void* const* d_in, const int* in_sizes, int n_in,
                              void* d_out, int out_size, void* d_ws, size_t ws_size,
                              hipStream_t stream) {
  const float* x    = (const float*)d_in[0];
  const float* W0   = (const float*)d_in[1];
  const float* b0   = (const float*)d_in[2];
  const float* W1   = (const float*)d_in[3];
  const float* b1   = (const float*)d_in[4];
  const float* W2   = (const float*)d_in[5];
  const float* b2   = (const float*)d_in[6];
  const int*   esrc = (const int*)d_in[7];
  const int*   edst = (const int*)d_in[8];
  float* out = (float*)d_out;

  // Workspace layout (4B units):
  //   norm_out[NP] norm_in[NP] row_ptr[NP](int) csr_src[NE](int)
  //   m[NN*64] h[NN*64]
  // Transients (cnt_in/cnt_out/cursor/partial) alias the h region (used only
  // during CSR build, before any gather writes h).  Total = 57.5 MB.
  float* f        = (float*)d_ws;
  float* norm_out = f;
  float* norm_in  = f + NP;
  int*   row_ptr  = (int*)(f + 2 * NP);
  int*   csr_src  = row_ptr + NP;
  float* m        = (float*)(csr_src + NE);
  float* h        = m + NN * 64;
  int*   cnt_out  = (int*)h;
  int*   cnt_in   = cnt_out + NP;
  int*   cursor   = cnt_in + NP;
  int*   partial  = cursor + NP;

  // --- CSR build (dst-sorted) + norms ---
  hipMemsetAsync(cnt_out, 0, 2 * NP * sizeof(int), stream);
  hist_kernel<<<(NE + 255) / 256, 256, 0, stream>>>(esrc, edst, cnt_out, cnt_in);
  norm_kernel<<<(NN + 255) / 256, 256, 0, stream>>>(cnt_out, cnt_in, norm_out, norm_in);
  chunk_sum_kernel<<<NBLK, 256, 0, stream>>>(cnt_in, partial);
  partial_scan_kernel<<<1, 128, 0, stream>>>(partial);
  chunk_scan_kernel<<<NBLK, 256, 0, stream>>>(cnt_in, partial, row_ptr, cursor);
  fill_kernel<<<(NE + 255) / 256, 256, 0, stream>>>(esrc, edst, cursor, csr_src);

  const int gb = (NN + 63) / 64;
  const int gg = (NN + 3) / 4;

  // Layer 0: m = (x*norm_out) @ W0 ; h = relu(agg*norm_in + b0)*norm_out
  gemm_kernel<128, 64, true><<<gb, 256, 0, stream>>>(x, W0, norm_out, m);
  gather_kernel<64, true><<<gg, 256, 0, stream>>>(m, row_ptr, csr_src, norm_in, norm_out, b0, h);

  // Layer 1: m = h @ W1 ; h = relu(agg*norm_in + b1)*norm_out
  gemm_kernel<64, 64, false><<<gb, 256, 0, stream>>>(h, W1, nullptr, m);
  gather_kernel<64, true><<<gg, 256, 0, stream>>>(m, row_ptr, csr_src, norm_in, norm_out, b1, h);

  // Layer 2: m = h @ W2 (40 cols) ; out = agg*norm_in + b2
  gemm_kernel<64, 40, false><<<gb, 256, 0, stream>>>(h, W2, nullptr, m);
  gather_kernel<40, false><<<gg, 256, 0, stream>>>(m, row_ptr, csr_src, norm_in, norm_out, b2, out);
}